// Round 8
// baseline (232.580 us; speedup 1.0000x reference)
//
#include <hip/hip_runtime.h>
#include <math.h>

// out[b, l, d] = x[b, l, d] + pe[l, d]
// pe[l, 0:128]   : interleaved sin/cos of row * freq_m   (m = 0..63)
// pe[l, 128:256] : interleaved sin/cos of col * freq_m
// freq_m = exp(-m * ln(10000)/64),  l = row * w + col,  d_model = 256
//
// Two-dispatch design: (1) pe_table_kernel generates the L*256-float PE table
// (16.8 MB @ L=16384) into the workspace; (2) pe_add_table is then a pure
// copy-with-add (~15 insts/thread, table reads L2/L3-resident), removing the
// 6-transcendental burst per float4 that is the last structural difference
// from the 6.29 TB/s float4-copy ceiling. h/w live on DEVICE, so both kernels
// make the SAME device-side capacity check (span*16 <= ws_size); if the
// workspace is too small the main kernel falls back to inline math (verified
// round-5 path). Table is regenerated every call (graph-capture safe, ~3 us).

typedef float f32x4 __attribute__((ext_vector_type(4)));

__device__ __forceinline__ f32x4 pe_value(unsigned int l, unsigned int j,
                                          unsigned int ww, bool wpow2,
                                          unsigned int wshift)
{
    unsigned int row, col;
    if (wpow2) { row = l >> wshift; col = l & (ww - 1u); }
    else       { row = l / ww;      col = l - row * ww; }

    const unsigned int d0 = j << 2;
    const unsigned int m0 = (d0 & 127u) >> 1;
    const float pos = (float)((d0 < 128u) ? row : col);

    const float cstep = 0.14391156831212787f;  // ln(10000)/64
    const float f0 = __expf(-(float)m0 * cstep);
    const float f1 = __expf(-(float)(m0 + 1u) * cstep);

    float s0, c0, s1, c1;
    __sincosf(pos * f0, &s0, &c0);
    __sincosf(pos * f1, &s1, &c1);
    return (f32x4){ s0, c0, s1, c1 };
}

__global__ __launch_bounds__(256) void pe_table_kernel(
    const int* __restrict__ hp,
    const int* __restrict__ wp,
    f32x4* __restrict__ tbl,
    unsigned long long ws_bytes)
{
    const unsigned int ww = (unsigned int)(*wp);
    const unsigned int hh = (unsigned int)(*hp);
    const unsigned int L  = hh * ww;
    const unsigned int span = L << 6;            // float4s in the table
    if ((unsigned long long)span * 16ull > ws_bytes) return;  // no room: skip

    const bool wpow2 = (ww & (ww - 1u)) == 0u;
    const unsigned int wshift = (unsigned int)__builtin_ctz(ww);

    const unsigned int stride = gridDim.x * blockDim.x;
    for (unsigned int u = blockIdx.x * blockDim.x + threadIdx.x;
         u < span; u += stride) {
        tbl[u] = pe_value(u >> 6, u & 63u, ww, wpow2, wshift);
    }
}

__global__ __launch_bounds__(256) void pe_add_table(
    const float* __restrict__ x,
    const int* __restrict__ hp,
    const int* __restrict__ wp,
    const f32x4* __restrict__ tbl,
    float* __restrict__ out,
    unsigned int n4,
    unsigned long long ws_bytes)
{
    const unsigned int idx = blockIdx.x * blockDim.x + threadIdx.x;
    if (idx >= n4) return;

    const unsigned int ww = (unsigned int)(*wp);
    const unsigned int hh = (unsigned int)(*hp);
    const unsigned int L  = hh * ww;
    const unsigned int span = L << 6;

    const f32x4 xv = reinterpret_cast<const f32x4*>(x)[idx];
    f32x4 pe;

    if ((unsigned long long)span * 16ull <= ws_bytes) {
        // table path (wave-uniform branch)
        unsigned int ti;
        if ((span & (span - 1u)) == 0u) ti = idx & (span - 1u);
        else                            ti = idx % span;
        pe = tbl[ti];
    } else {
        // inline fallback (verified round-5 math)
        const bool wpow2 = (ww & (ww - 1u)) == 0u;
        const unsigned int wshift = (unsigned int)__builtin_ctz(ww);
        const unsigned int t = idx >> 6;
        unsigned int l;
        if ((L & (L - 1u)) == 0u) l = t & (L - 1u);
        else                      l = t % L;
        pe = pe_value(l, idx & 63u, ww, wpow2, wshift);
    }

    reinterpret_cast<f32x4*>(out)[idx] = xv + pe;
}

extern "C" void kernel_launch(void* const* d_in, const int* in_sizes, int n_in,
                              void* d_out, int out_size, void* d_ws, size_t ws_size,
                              hipStream_t stream) {
    const float* x = (const float*)d_in[0];
    const int* hp  = (const int*)d_in[1];
    const int* wp  = (const int*)d_in[2];
    float* out     = (float*)d_out;
    f32x4* tbl     = (f32x4*)d_ws;

    // out_size is in float elements -> float4 count = /4 (verified)
    const unsigned int n4 = (unsigned int)(out_size / 4);
    const unsigned long long wsb = (unsigned long long)ws_size;

    // table gen: grid-stride over span (device-known); 4096 blocks covers
    // L=16384 exactly at 1 iter/thread.
    pe_table_kernel<<<4096, 256, 0, stream>>>(hp, wp, tbl, wsb);

    const unsigned int blocks = (n4 + 255u) / 256u;
    pe_add_table<<<blocks, 256, 0, stream>>>(x, hp, wp, tbl, out, n4, wsb);
}